// Round 1
// baseline (440.896 us; speedup 1.0000x reference)
//
#include <hip/hip_runtime.h>
#include <math.h>

#define BB 8
#define PP 1000
#define NN 1000
#define EE 128
#define HH 8
#define DD 16

#define INV_SQRT_E 0.08838834764831845f   // 1/sqrt(128)
#define INV_SQRT_D 0.25f                   // 1/sqrt(16)

__device__ __forceinline__ float sigmoid_fast(float x) {
    return 1.f / (1.f + __expf(-x));
}
__device__ __forceinline__ float tanh_fast(float x) {
    x = fminf(fmaxf(x, -15.f), 15.f);
    float e = __expf(2.f * x);
    return (e - 1.f) / (e + 1.f);
}

// ---------------------------------------------------------------------------
// K1: kv projections. A=[8000,128] (nodes), W=[128,128] (one of 4 selected by
// blockIdx.y), output in [B,H,N,D] layout. Tile 64 rows x 128 cols, k-step 16.
// ---------------------------------------------------------------------------
__global__ __launch_bounds__(256) void kv_proj_kernel(
    const float* __restrict__ A,
    const float* __restrict__ Wk_s, const float* __restrict__ Wv_s,
    const float* __restrict__ Wk_t, const float* __restrict__ Wv_t,
    float* __restrict__ k_s, float* __restrict__ v_s,
    float* __restrict__ k_t, float* __restrict__ v_t)
{
    const int wsel = blockIdx.y;
    const float* W = (wsel == 0) ? Wk_s : (wsel == 1) ? Wv_s : (wsel == 2) ? Wk_t : Wv_t;
    float* O = (wsel == 0) ? k_s : (wsel == 1) ? v_s : (wsel == 2) ? k_t : v_t;
    const int r0 = blockIdx.x * 64;
    __shared__ float As[64][16];
    __shared__ float Ws[16][128];
    const int tid = threadIdx.x;
    const int rg = tid >> 5;    // 0..7  -> rows rg*8 .. rg*8+7
    const int cg = tid & 31;    // 0..31 -> cols cg*4 .. cg*4+3
    float acc[8][4] = {};

    for (int k0 = 0; k0 < 128; k0 += 16) {
        {   // A tile: 64x16
            int row = tid >> 2, seg = tid & 3;
            float4 av = *(const float4*)&A[(size_t)(r0 + row) * 128 + k0 + seg * 4];
            *(float4*)&As[row][seg * 4] = av;
        }
        {   // W tile: 16x128
            int kk = tid >> 4, c = (tid & 15) * 8;
            *(float4*)&Ws[kk][c]     = *(const float4*)&W[(size_t)(k0 + kk) * 128 + c];
            *(float4*)&Ws[kk][c + 4] = *(const float4*)&W[(size_t)(k0 + kk) * 128 + c + 4];
        }
        __syncthreads();
        #pragma unroll
        for (int k = 0; k < 16; ++k) {
            float4 w = *(const float4*)&Ws[k][cg * 4];
            #pragma unroll
            for (int r = 0; r < 8; ++r) {
                float a = As[rg * 8 + r][k];
                acc[r][0] = fmaf(a, w.x, acc[r][0]);
                acc[r][1] = fmaf(a, w.y, acc[r][1]);
                acc[r][2] = fmaf(a, w.z, acc[r][2]);
                acc[r][3] = fmaf(a, w.w, acc[r][3]);
            }
        }
        __syncthreads();
    }
    const int c = cg * 4;
    const int h = c >> 4, d = c & 15;
    #pragma unroll
    for (int r = 0; r < 8; ++r) {
        int row = r0 + rg * 8 + r;
        int b = row / 1000, n = row % 1000;
        float4 v = make_float4(acc[r][0], acc[r][1], acc[r][2], acc[r][3]);
        *(float4*)&O[((size_t)(b * HH + h) * 1000 + n) * 16 + d] = v;
    }
}

// ---------------------------------------------------------------------------
// K2: q_shared / q_task / gate projections. A = concat(eln[128], attr[4]) (K=132),
// W selected by blockIdx.y among {Wq_s, Wq_t, Wg} (each [132,128]).
// ---------------------------------------------------------------------------
__global__ __launch_bounds__(256) void q_proj_kernel(
    const float* __restrict__ eln, const float* __restrict__ attr,
    const float* __restrict__ Wq_s, const float* __restrict__ Wq_t,
    const float* __restrict__ Wg, const float* __restrict__ bg,
    float* __restrict__ q_s, float* __restrict__ q_t, float* __restrict__ gate)
{
    const int wsel = blockIdx.y;
    const float* W = (wsel == 0) ? Wq_s : (wsel == 1) ? Wq_t : Wg;
    const int r0 = blockIdx.x * 64;
    __shared__ float As[64][16];
    __shared__ float Ws[16][128];
    const int tid = threadIdx.x;
    const int rg = tid >> 5;
    const int cg = tid & 31;
    float acc[8][4] = {};

    for (int k0 = 0; k0 < 144; k0 += 16) {
        {   // A tile (implicit concat, zero-padded to 144)
            int row = tid >> 2, seg = tid & 3;
            int k = k0 + seg * 4;
            float4 av = make_float4(0.f, 0.f, 0.f, 0.f);
            if (k + 3 < 128)      av = *(const float4*)&eln[(size_t)(r0 + row) * 128 + k];
            else if (k == 128)    av = *(const float4*)&attr[(size_t)(r0 + row) * 4];
            *(float4*)&As[row][seg * 4] = av;
        }
        {   // W tile (rows beyond 132 are zero)
            int kk = tid >> 4, c = (tid & 15) * 8;
            int k = k0 + kk;
            float4 w0 = make_float4(0.f, 0.f, 0.f, 0.f), w1 = w0;
            if (k < 132) {
                w0 = *(const float4*)&W[(size_t)k * 128 + c];
                w1 = *(const float4*)&W[(size_t)k * 128 + c + 4];
            }
            *(float4*)&Ws[kk][c]     = w0;
            *(float4*)&Ws[kk][c + 4] = w1;
        }
        __syncthreads();
        #pragma unroll
        for (int k = 0; k < 16; ++k) {
            float4 w = *(const float4*)&Ws[k][cg * 4];
            #pragma unroll
            for (int r = 0; r < 8; ++r) {
                float a = As[rg * 8 + r][k];
                acc[r][0] = fmaf(a, w.x, acc[r][0]);
                acc[r][1] = fmaf(a, w.y, acc[r][1]);
                acc[r][2] = fmaf(a, w.z, acc[r][2]);
                acc[r][3] = fmaf(a, w.w, acc[r][3]);
            }
        }
        __syncthreads();
    }
    const int c = cg * 4;
    if (wsel < 2) {
        float* Qo = (wsel == 0) ? q_s : q_t;
        const int h = c >> 4, d = c & 15;
        #pragma unroll
        for (int r = 0; r < 8; ++r) {
            int row = r0 + rg * 8 + r;
            int b = row / 1000, p = row % 1000;
            *(float4*)&Qo[((size_t)(b * HH + h) * 1000 + p) * 16 + d] =
                make_float4(acc[r][0], acc[r][1], acc[r][2], acc[r][3]);
        }
    } else {
        float4 bgv = *(const float4*)&bg[c];
        #pragma unroll
        for (int r = 0; r < 8; ++r) {
            int row = r0 + rg * 8 + r;
            float4 g;
            g.x = sigmoid_fast(acc[r][0] + bgv.x);
            g.y = sigmoid_fast(acc[r][1] + bgv.y);
            g.z = sigmoid_fast(acc[r][2] + bgv.z);
            g.w = sigmoid_fast(acc[r][3] + bgv.w);
            *(float4*)&gate[(size_t)row * 128 + c] = g;
        }
    }
}

// ---------------------------------------------------------------------------
// K3: attention. One thread owns one query p; K/V tiles staged in LDS (broadcast
// reads); online softmax with single-exp common path. blockIdx.y = h*2 + branch.
// Output att_{s,t} in [B,P,H*D] layout for the combine GEMM.
// ---------------------------------------------------------------------------
__global__ __launch_bounds__(256) void attn_kernel(
    const float* __restrict__ q_s, const float* __restrict__ q_t,
    const float* __restrict__ k_s, const float* __restrict__ k_t,
    const float* __restrict__ v_s, const float* __restrict__ v_t,
    const float* __restrict__ mask,
    float* __restrict__ att_s, float* __restrict__ att_t)
{
    const int b  = blockIdx.z;
    const int h  = blockIdx.y >> 1;
    const int br = blockIdx.y & 1;
    const float* Q = br ? q_t : q_s;
    const float* K = br ? k_t : k_s;
    const float* V = br ? v_t : v_s;
    float* O       = br ? att_t : att_s;
    const int tid = threadIdx.x;
    const size_t bh = ((size_t)b * HH + h) * 1000;

    __shared__ float Ks[128 * 16];
    __shared__ float Vs[128 * 16];

    const int p = blockIdx.x * 256 + tid;
    const bool act = p < PP;

    float q[16];
    #pragma unroll
    for (int d2 = 0; d2 < 16; ++d2) q[d2] = 0.f;
    if (act) {
        const float4* qp = (const float4*)(Q + (bh + p) * 16);
        *(float4*)&q[0]  = qp[0];
        *(float4*)&q[4]  = qp[1];
        *(float4*)&q[8]  = qp[2];
        *(float4*)&q[12] = qp[3];
    }
    float o[16];
    #pragma unroll
    for (int d2 = 0; d2 < 16; ++d2) o[d2] = 0.f;
    float m = -INFINITY, l = 0.f;
    const float* mrow = mask + ((size_t)b * PP + (act ? p : 0)) * NN;

    for (int n0 = 0; n0 < NN; n0 += 128) {
        const int ntile = min(128, NN - n0);
        const int nfl = ntile * 16;
        __syncthreads();
        #pragma unroll
        for (int it = 0; it < 2; ++it) {
            int i = tid * 4 + it * 1024;
            if (i < nfl) {
                *(float4*)&Ks[i] = *(const float4*)&K[(bh + n0) * 16 + i];
                *(float4*)&Vs[i] = *(const float4*)&V[(bh + n0) * 16 + i];
            }
        }
        __syncthreads();
        for (int nn = 0; nn < ntile; nn += 4) {
            float4 mk4 = act ? *(const float4*)&mrow[n0 + nn] : make_float4(0.f, 0.f, 0.f, 0.f);
            float mk[4] = {mk4.x, mk4.y, mk4.z, mk4.w};
            #pragma unroll
            for (int j = 0; j < 4; ++j) {
                float kk[16], vv[16];
                *(float4*)&kk[0]  = *(const float4*)&Ks[(nn + j) * 16];
                *(float4*)&kk[4]  = *(const float4*)&Ks[(nn + j) * 16 + 4];
                *(float4*)&kk[8]  = *(const float4*)&Ks[(nn + j) * 16 + 8];
                *(float4*)&kk[12] = *(const float4*)&Ks[(nn + j) * 16 + 12];
                *(float4*)&vv[0]  = *(const float4*)&Vs[(nn + j) * 16];
                *(float4*)&vv[4]  = *(const float4*)&Vs[(nn + j) * 16 + 4];
                *(float4*)&vv[8]  = *(const float4*)&Vs[(nn + j) * 16 + 8];
                *(float4*)&vv[12] = *(const float4*)&Vs[(nn + j) * 16 + 12];
                float s = 0.f;
                #pragma unroll
                for (int d2 = 0; d2 < 16; ++d2) s = fmaf(q[d2], kk[d2], s);
                s = s * INV_SQRT_D + mk[j];
                if (s <= m) {
                    float e = __expf(s - m);
                    l += e;
                    #pragma unroll
                    for (int d2 = 0; d2 < 16; ++d2) o[d2] = fmaf(e, vv[d2], o[d2]);
                } else {
                    float cr = __expf(m - s);
                    m = s;
                    l = fmaf(l, cr, 1.f);
                    #pragma unroll
                    for (int d2 = 0; d2 < 16; ++d2) o[d2] = fmaf(o[d2], cr, vv[d2]);
                }
            }
        }
    }
    if (act) {
        float inv = 1.f / l;
        float* op = O + ((size_t)b * PP + p) * 128 + h * 16;
        *(float4*)&op[0]  = make_float4(o[0] * inv,  o[1] * inv,  o[2] * inv,  o[3] * inv);
        *(float4*)&op[4]  = make_float4(o[4] * inv,  o[5] * inv,  o[6] * inv,  o[7] * inv);
        *(float4*)&op[8]  = make_float4(o[8] * inv,  o[9] * inv,  o[10] * inv, o[11] * inv);
        *(float4*)&op[12] = make_float4(o[12] * inv, o[13] * inv, o[14] * inv, o[15] * inv);
    }
}

// ---------------------------------------------------------------------------
// K4: combine: gated = g*(att_s@Wc_s + bc_s) + (1-g)*(att_t@Wc_t + bc_t)
// Tile 32 rows x 128 cols, both branches per block.
// ---------------------------------------------------------------------------
__global__ __launch_bounds__(256) void combine_kernel(
    const float* __restrict__ att_s, const float* __restrict__ att_t,
    const float* __restrict__ Wc_s, const float* __restrict__ bc_s,
    const float* __restrict__ Wc_t, const float* __restrict__ bc_t,
    const float* __restrict__ gate, float* __restrict__ gated)
{
    const int r0 = blockIdx.x * 32;
    __shared__ float As[32][16], At[32][16];
    __shared__ float Ws[16][128], Wt[16][128];
    const int tid = threadIdx.x;
    const int rg = tid >> 5;   // 0..7 -> rows rg*4..rg*4+3
    const int cg = tid & 31;
    float accs[4][4] = {}, acct[4][4] = {};

    for (int k0 = 0; k0 < 128; k0 += 16) {
        {   // A tiles: 32x16 each, half the threads per matrix
            int t2 = tid & 127, row = t2 >> 2, seg = t2 & 3;
            const float* src = (tid < 128) ? att_s : att_t;
            float* dst = (tid < 128) ? &As[row][seg * 4] : &At[row][seg * 4];
            *(float4*)dst = *(const float4*)&src[(size_t)(r0 + row) * 128 + k0 + seg * 4];
        }
        {   // W tiles
            int kk = tid >> 4, c = (tid & 15) * 8;
            *(float4*)&Ws[kk][c]     = *(const float4*)&Wc_s[(size_t)(k0 + kk) * 128 + c];
            *(float4*)&Ws[kk][c + 4] = *(const float4*)&Wc_s[(size_t)(k0 + kk) * 128 + c + 4];
            *(float4*)&Wt[kk][c]     = *(const float4*)&Wc_t[(size_t)(k0 + kk) * 128 + c];
            *(float4*)&Wt[kk][c + 4] = *(const float4*)&Wc_t[(size_t)(k0 + kk) * 128 + c + 4];
        }
        __syncthreads();
        #pragma unroll
        for (int k = 0; k < 16; ++k) {
            float4 w1 = *(const float4*)&Ws[k][cg * 4];
            float4 w2 = *(const float4*)&Wt[k][cg * 4];
            #pragma unroll
            for (int r = 0; r < 4; ++r) {
                float a1 = As[rg * 4 + r][k];
                float a2 = At[rg * 4 + r][k];
                accs[r][0] = fmaf(a1, w1.x, accs[r][0]);
                accs[r][1] = fmaf(a1, w1.y, accs[r][1]);
                accs[r][2] = fmaf(a1, w1.z, accs[r][2]);
                accs[r][3] = fmaf(a1, w1.w, accs[r][3]);
                acct[r][0] = fmaf(a2, w2.x, acct[r][0]);
                acct[r][1] = fmaf(a2, w2.y, acct[r][1]);
                acct[r][2] = fmaf(a2, w2.z, acct[r][2]);
                acct[r][3] = fmaf(a2, w2.w, acct[r][3]);
            }
        }
        __syncthreads();
    }
    const int c = cg * 4;
    float4 b1 = *(const float4*)&bc_s[c];
    float4 b2 = *(const float4*)&bc_t[c];
    #pragma unroll
    for (int r = 0; r < 4; ++r) {
        int row = r0 + rg * 4 + r;
        float4 g = *(const float4*)&gate[(size_t)row * 128 + c];
        float4 ov;
        ov.x = g.x * (accs[r][0] + b1.x) + (1.f - g.x) * (acct[r][0] + b2.x);
        ov.y = g.y * (accs[r][1] + b1.y) + (1.f - g.y) * (acct[r][1] + b2.y);
        ov.z = g.z * (accs[r][2] + b1.z) + (1.f - g.z) * (acct[r][2] + b2.z);
        ov.w = g.w * (accs[r][3] + b1.w) + (1.f - g.w) * (acct[r][3] + b2.w);
        *(float4*)&gated[(size_t)row * 128 + c] = ov;
    }
}

// ---------------------------------------------------------------------------
// K5: pointer scores: out[b,p,n] = 10*tanh((gated[b,p,:].nodes[b,n,:])/sqrt(E)) + mask
// Batched GEMM vs nodes^T; B tile transposed into LDS (2-way bank alias = free).
// ---------------------------------------------------------------------------
__global__ __launch_bounds__(256) void pointer_kernel(
    const float* __restrict__ gated, const float* __restrict__ nodes,
    const float* __restrict__ mask, float* __restrict__ out)
{
    const int b  = blockIdx.z;
    const int p0 = blockIdx.y * 64;
    const int n0 = blockIdx.x * 128;
    __shared__ float As[64][16];
    __shared__ float BsT[16][128];
    const int tid = threadIdx.x;
    const int rg = tid >> 5;
    const int cg = tid & 31;
    float acc[8][4] = {};

    for (int k0 = 0; k0 < 128; k0 += 16) {
        {   // A tile (gated rows)
            int row = tid >> 2, seg = tid & 3;
            int pp = p0 + row;
            float4 av = make_float4(0.f, 0.f, 0.f, 0.f);
            if (pp < PP) av = *(const float4*)&gated[((size_t)b * PP + pp) * 128 + k0 + seg * 4];
            *(float4*)&As[row][seg * 4] = av;
        }
        {   // B tile (nodes rows) -> transposed store
            int row = tid >> 1, seg = (tid & 1) * 8;
            int nr = n0 + row;
            float4 b0 = make_float4(0.f, 0.f, 0.f, 0.f), b1 = b0;
            if (nr < NN) {
                b0 = *(const float4*)&nodes[((size_t)b * NN + nr) * 128 + k0 + seg];
                b1 = *(const float4*)&nodes[((size_t)b * NN + nr) * 128 + k0 + seg + 4];
            }
            BsT[seg + 0][row] = b0.x; BsT[seg + 1][row] = b0.y;
            BsT[seg + 2][row] = b0.z; BsT[seg + 3][row] = b0.w;
            BsT[seg + 4][row] = b1.x; BsT[seg + 5][row] = b1.y;
            BsT[seg + 6][row] = b1.z; BsT[seg + 7][row] = b1.w;
        }
        __syncthreads();
        #pragma unroll
        for (int k = 0; k < 16; ++k) {
            float4 w = *(const float4*)&BsT[k][cg * 4];
            #pragma unroll
            for (int r = 0; r < 8; ++r) {
                float a = As[rg * 8 + r][k];
                acc[r][0] = fmaf(a, w.x, acc[r][0]);
                acc[r][1] = fmaf(a, w.y, acc[r][1]);
                acc[r][2] = fmaf(a, w.z, acc[r][2]);
                acc[r][3] = fmaf(a, w.w, acc[r][3]);
            }
        }
        __syncthreads();
    }
    const int n = n0 + cg * 4;
    if (n < NN) {
        #pragma unroll
        for (int r = 0; r < 8; ++r) {
            int pp = p0 + rg * 8 + r;
            if (pp < PP) {
                float4 mk = *(const float4*)&mask[((size_t)b * PP + pp) * NN + n];
                float4 ov;
                ov.x = 10.f * tanh_fast(acc[r][0] * INV_SQRT_E) + mk.x;
                ov.y = 10.f * tanh_fast(acc[r][1] * INV_SQRT_E) + mk.y;
                ov.z = 10.f * tanh_fast(acc[r][2] * INV_SQRT_E) + mk.z;
                ov.w = 10.f * tanh_fast(acc[r][3] * INV_SQRT_E) + mk.w;
                *(float4*)&out[((size_t)b * PP + pp) * NN + n] = ov;
            }
        }
    }
}

// ---------------------------------------------------------------------------
// K6: row softmax in-place over d_out [8000, 1000]. One wave per row.
// ---------------------------------------------------------------------------
__global__ __launch_bounds__(256) void softmax_kernel(float* __restrict__ out)
{
    const int row = blockIdx.x * 4 + (threadIdx.x >> 6);
    const int lane = threadIdx.x & 63;
    float* r = out + (size_t)row * NN;
    float v[16];
    float m = -INFINITY;
    #pragma unroll
    for (int j = 0; j < 4; ++j) {
        int n = j * 256 + lane * 4;
        float4 x = make_float4(-INFINITY, -INFINITY, -INFINITY, -INFINITY);
        if (n < NN) x = *(const float4*)&r[n];
        v[j * 4 + 0] = x.x; v[j * 4 + 1] = x.y; v[j * 4 + 2] = x.z; v[j * 4 + 3] = x.w;
        m = fmaxf(m, fmaxf(fmaxf(x.x, x.y), fmaxf(x.z, x.w)));
    }
    #pragma unroll
    for (int off = 1; off < 64; off <<= 1) m = fmaxf(m, __shfl_xor(m, off, 64));
    float sum = 0.f;
    #pragma unroll
    for (int j = 0; j < 16; ++j) { v[j] = __expf(v[j] - m); sum += v[j]; }
    #pragma unroll
    for (int off = 1; off < 64; off <<= 1) sum += __shfl_xor(sum, off, 64);
    float inv = 1.f / sum;
    #pragma unroll
    for (int j = 0; j < 4; ++j) {
        int n = j * 256 + lane * 4;
        if (n < NN) {
            *(float4*)&r[n] = make_float4(v[j * 4 + 0] * inv, v[j * 4 + 1] * inv,
                                          v[j * 4 + 2] * inv, v[j * 4 + 3] * inv);
        }
    }
}

// ---------------------------------------------------------------------------
extern "C" void kernel_launch(void* const* d_in, const int* in_sizes, int n_in,
                              void* d_out, int out_size, void* d_ws, size_t ws_size,
                              hipStream_t stream)
{
    const float* eln   = (const float*)d_in[0];
    const float* attr  = (const float*)d_in[1];
    const float* nodes = (const float*)d_in[2];
    const float* mask  = (const float*)d_in[3];
    const float* Wq_s  = (const float*)d_in[4];
    const float* Wk_s  = (const float*)d_in[5];
    const float* Wv_s  = (const float*)d_in[6];
    const float* Wq_t  = (const float*)d_in[7];
    const float* Wk_t  = (const float*)d_in[8];
    const float* Wv_t  = (const float*)d_in[9];
    const float* Wc_s  = (const float*)d_in[10];
    const float* bc_s  = (const float*)d_in[11];
    const float* Wc_t  = (const float*)d_in[12];
    const float* bc_t  = (const float*)d_in[13];
    const float* Wg    = (const float*)d_in[14];
    const float* bg    = (const float*)d_in[15];
    float* out = (float*)d_out;

    float* ws = (float*)d_ws;
    const size_t SZ = 1024000;   // B*H*1000*16 == B*1000*128
    float* k_s   = ws;
    float* v_s   = k_s   + SZ;
    float* k_t   = v_s   + SZ;
    float* v_t   = k_t   + SZ;
    float* q_s   = v_t   + SZ;
    float* q_t   = q_s   + SZ;
    float* gate  = q_t   + SZ;
    float* att_s = gate  + SZ;
    float* att_t = att_s + SZ;
    float* gated = att_t + SZ;

    kv_proj_kernel<<<dim3(125, 4), 256, 0, stream>>>(
        nodes, Wk_s, Wv_s, Wk_t, Wv_t, k_s, v_s, k_t, v_t);
    q_proj_kernel<<<dim3(125, 3), 256, 0, stream>>>(
        eln, attr, Wq_s, Wq_t, Wg, bg, q_s, q_t, gate);
    attn_kernel<<<dim3(4, 16, 8), 256, 0, stream>>>(
        q_s, q_t, k_s, k_t, v_s, v_t, mask, att_s, att_t);
    combine_kernel<<<dim3(250), 256, 0, stream>>>(
        att_s, att_t, Wc_s, bc_s, Wc_t, bc_t, gate, gated);
    pointer_kernel<<<dim3(8, 16, 8), 256, 0, stream>>>(
        gated, nodes, mask, out);
    softmax_kernel<<<dim3(2000), 256, 0, stream>>>(out);
}

// Round 2
// 315.471 us; speedup vs baseline: 1.3976x; 1.3976x over previous
//
#include <hip/hip_runtime.h>
#include <math.h>

#define BB 8
#define PP 1000
#define NN 1000
#define EE 128
#define HH 8
#define DD 16

#define INV_SQRT_E 0.08838834764831845f   // 1/sqrt(128)
#define INV_SQRT_D 0.25f                   // 1/sqrt(16)

typedef short short8_t __attribute__((ext_vector_type(8)));
typedef float f32x4    __attribute__((ext_vector_type(4)));
typedef __bf16 bf16x4  __attribute__((ext_vector_type(4)));

__device__ __forceinline__ float sigmoid_fast(float x) {
    return 1.f / (1.f + __expf(-x));
}
__device__ __forceinline__ float tanh_fast(float x) {
    x = fminf(fmaxf(x, -15.f), 15.f);
    float e = __expf(2.f * x);
    return (e - 1.f) / (e + 1.f);
}

__device__ __forceinline__ f32x4 mfma16(short8_t a, short8_t b, f32x4 c) {
    return __builtin_amdgcn_mfma_f32_16x16x32_bf16(a, b, c, 0, 0, 0);
}

// max across the 16 lanes of a DPP row (butterfly: quad_perm xor1, xor2,
// row_half_mirror, row_mirror). Pure VALU — no LDS pipe.
__device__ __forceinline__ float max16(float x) {
    int v;
    v = __builtin_amdgcn_update_dpp(0, __builtin_bit_cast(int, x), 0xB1, 0xF, 0xF, true);
    x = fmaxf(x, __builtin_bit_cast(float, v));
    v = __builtin_amdgcn_update_dpp(0, __builtin_bit_cast(int, x), 0x4E, 0xF, 0xF, true);
    x = fmaxf(x, __builtin_bit_cast(float, v));
    v = __builtin_amdgcn_update_dpp(0, __builtin_bit_cast(int, x), 0x141, 0xF, 0xF, true);
    x = fmaxf(x, __builtin_bit_cast(float, v));
    v = __builtin_amdgcn_update_dpp(0, __builtin_bit_cast(int, x), 0x140, 0xF, 0xF, true);
    x = fmaxf(x, __builtin_bit_cast(float, v));
    return x;
}

__device__ __forceinline__ unsigned int pack_bf16(float a, float b) {
    __bf16 x = (__bf16)a, y = (__bf16)b;
    unsigned short ux = __builtin_bit_cast(unsigned short, x);
    unsigned short uy = __builtin_bit_cast(unsigned short, y);
    return (unsigned int)ux | ((unsigned int)uy << 16);
}

// ---------------------------------------------------------------------------
// K1: kv projections -> bf16. K stored [bh][n][d] (row-major d). V stored
// TRANSPOSED + key-permuted: [bh][d][pos], rows padded to 1024 slots; within
// each 32-key block, key r<16 -> slot 2r, r>=16 -> slot 2(r-16)+1 (matches the
// packed-pair LDS layout the attention kernel writes for P).
// ---------------------------------------------------------------------------
__global__ __launch_bounds__(256) void kv_proj_kernel(
    const float* __restrict__ A,
    const float* __restrict__ Wk_s, const float* __restrict__ Wv_s,
    const float* __restrict__ Wk_t, const float* __restrict__ Wv_t,
    __bf16* __restrict__ kb_s, __bf16* __restrict__ vt_s,
    __bf16* __restrict__ kb_t, __bf16* __restrict__ vt_t)
{
    const int wsel = blockIdx.y;
    const float* W = (wsel == 0) ? Wk_s : (wsel == 1) ? Wv_s : (wsel == 2) ? Wk_t : Wv_t;
    __bf16* KO = (wsel == 0) ? kb_s : kb_t;
    __bf16* VO = (wsel == 1) ? vt_s : vt_t;
    const int r0 = blockIdx.x * 64;
    __shared__ float As[64][16];
    __shared__ float Ws[16][128];
    const int tid = threadIdx.x;
    const int rg = tid >> 5;
    const int cg = tid & 31;
    float acc[8][4] = {};

    for (int k0 = 0; k0 < 128; k0 += 16) {
        {
            int row = tid >> 2, seg = tid & 3;
            float4 av = *(const float4*)&A[(size_t)(r0 + row) * 128 + k0 + seg * 4];
            *(float4*)&As[row][seg * 4] = av;
        }
        {
            int kk = tid >> 4, c = (tid & 15) * 8;
            *(float4*)&Ws[kk][c]     = *(const float4*)&W[(size_t)(k0 + kk) * 128 + c];
            *(float4*)&Ws[kk][c + 4] = *(const float4*)&W[(size_t)(k0 + kk) * 128 + c + 4];
        }
        __syncthreads();
        #pragma unroll
        for (int k = 0; k < 16; ++k) {
            float4 w = *(const float4*)&Ws[k][cg * 4];
            #pragma unroll
            for (int r = 0; r < 8; ++r) {
                float a = As[rg * 8 + r][k];
                acc[r][0] = fmaf(a, w.x, acc[r][0]);
                acc[r][1] = fmaf(a, w.y, acc[r][1]);
                acc[r][2] = fmaf(a, w.z, acc[r][2]);
                acc[r][3] = fmaf(a, w.w, acc[r][3]);
            }
        }
        __syncthreads();
    }
    const int c = cg * 4;
    const int h = c >> 4, d = c & 15;
    if ((wsel & 1) == 0) {
        #pragma unroll
        for (int r = 0; r < 8; ++r) {
            int row = r0 + rg * 8 + r;
            int b = row / 1000, n = row % 1000;
            bf16x4 pk = { (__bf16)acc[r][0], (__bf16)acc[r][1],
                          (__bf16)acc[r][2], (__bf16)acc[r][3] };
            *(bf16x4*)&KO[(((size_t)(b * HH + h) * 1000 + n) << 4) + d] = pk;
        }
    } else {
        #pragma unroll
        for (int r = 0; r < 8; ++r) {
            int row = r0 + rg * 8 + r;
            int b = row / 1000, n = row % 1000;
            int rr = n & 31;
            int pos = (n & ~31) + ((rr < 16) ? (rr << 1) : (((rr - 16) << 1) | 1));
            #pragma unroll
            for (int i = 0; i < 4; ++i) {
                VO[((size_t)((b * HH + h) * 16 + d + i) << 10) + pos] = (__bf16)acc[r][i];
            }
        }
    }
}

// ---------------------------------------------------------------------------
// K2: q_shared / q_task (bf16 out, [bh][p][d]) and gate (fp32) projections.
// ---------------------------------------------------------------------------
__global__ __launch_bounds__(256) void q_proj_kernel(
    const float* __restrict__ eln, const float* __restrict__ attr,
    const float* __restrict__ Wq_s, const float* __restrict__ Wq_t,
    const float* __restrict__ Wg, const float* __restrict__ bg,
    __bf16* __restrict__ qb_s, __bf16* __restrict__ qb_t, float* __restrict__ gate)
{
    const int wsel = blockIdx.y;
    const float* W = (wsel == 0) ? Wq_s : (wsel == 1) ? Wq_t : Wg;
    const int r0 = blockIdx.x * 64;
    __shared__ float As[64][16];
    __shared__ float Ws[16][128];
    const int tid = threadIdx.x;
    const int rg = tid >> 5;
    const int cg = tid & 31;
    float acc[8][4] = {};

    for (int k0 = 0; k0 < 144; k0 += 16) {
        {
            int row = tid >> 2, seg = tid & 3;
            int k = k0 + seg * 4;
            float4 av = make_float4(0.f, 0.f, 0.f, 0.f);
            if (k + 3 < 128)      av = *(const float4*)&eln[(size_t)(r0 + row) * 128 + k];
            else if (k == 128)    av = *(const float4*)&attr[(size_t)(r0 + row) * 4];
            *(float4*)&As[row][seg * 4] = av;
        }
        {
            int kk = tid >> 4, c = (tid & 15) * 8;
            int k = k0 + kk;
            float4 w0 = make_float4(0.f, 0.f, 0.f, 0.f), w1 = w0;
            if (k < 132) {
                w0 = *(const float4*)&W[(size_t)k * 128 + c];
                w1 = *(const float4*)&W[(size_t)k * 128 + c + 4];
            }
            *(float4*)&Ws[kk][c]     = w0;
            *(float4*)&Ws[kk][c + 4] = w1;
        }
        __syncthreads();
        #pragma unroll
        for (int k = 0; k < 16; ++k) {
            float4 w = *(const float4*)&Ws[k][cg * 4];
            #pragma unroll
            for (int r = 0; r < 8; ++r) {
                float a = As[rg * 8 + r][k];
                acc[r][0] = fmaf(a, w.x, acc[r][0]);
                acc[r][1] = fmaf(a, w.y, acc[r][1]);
                acc[r][2] = fmaf(a, w.z, acc[r][2]);
                acc[r][3] = fmaf(a, w.w, acc[r][3]);
            }
        }
        __syncthreads();
    }
    const int c = cg * 4;
    if (wsel < 2) {
        __bf16* Qo = (wsel == 0) ? qb_s : qb_t;
        const int h = c >> 4, d = c & 15;
        #pragma unroll
        for (int r = 0; r < 8; ++r) {
            int row = r0 + rg * 8 + r;
            int b = row / 1000, p = row % 1000;
            bf16x4 pk = { (__bf16)acc[r][0], (__bf16)acc[r][1],
                          (__bf16)acc[r][2], (__bf16)acc[r][3] };
            *(bf16x4*)&Qo[(((size_t)(b * HH + h) * 1000 + p) << 4) + d] = pk;
        }
    } else {
        float4 bgv = *(const float4*)&bg[c];
        #pragma unroll
        for (int r = 0; r < 8; ++r) {
            int row = r0 + rg * 8 + r;
            float4 g;
            g.x = sigmoid_fast(acc[r][0] + bgv.x);
            g.y = sigmoid_fast(acc[r][1] + bgv.y);
            g.z = sigmoid_fast(acc[r][2] + bgv.z);
            g.w = sigmoid_fast(acc[r][3] + bgv.w);
            *(float4*)&gate[(size_t)row * 128 + c] = g;
        }
    }
}

// ---------------------------------------------------------------------------
// K3: MFMA flash attention. 1 wave = one (b,h,branch), 2 q-tiles of 16.
// Block = 4 waves (4 combos) sharing mask rows. Online softmax: row-max via
// DPP butterfly, row-sum l via MFMA vs ones-fragment. P round-trips through
// LDS as packed bf16 pairs (keys interleaved to match pre-permuted V).
// ---------------------------------------------------------------------------
__global__ __launch_bounds__(256) void attn_mfma_kernel(
    const __bf16* __restrict__ qb_s, const __bf16* __restrict__ qb_t,
    const __bf16* __restrict__ kb_s, const __bf16* __restrict__ kb_t,
    const __bf16* __restrict__ vt_s, const __bf16* __restrict__ vt_t,
    const float* __restrict__ mask,
    float* __restrict__ att_s, float* __restrict__ att_t)
{
    const int b    = blockIdx.z;
    const int wave = threadIdx.x >> 6;
    const int combo = blockIdx.y * 4 + wave;
    const int br = combo & 1;
    const int h  = combo >> 1;
    const __bf16* Q  = br ? qb_t : qb_s;
    const __bf16* K  = br ? kb_t : kb_s;
    const __bf16* Vt = br ? vt_t : vt_s;
    float* O         = br ? att_t : att_s;
    const int lane = threadIdx.x & 63;
    const int quad = lane >> 4, lq = lane & 15;
    const int bh = b * HH + h;
    const int p0 = blockIdx.x * 32;

    __shared__ unsigned int Plds[4][16][20];   // per-wave 16 rows x 16 uints, +4 pad

    // Q fragments (A-operand): m = lq (query), k = quad*8+j (d, padded 16->32)
    short8_t qA[2] = {};
    if (quad < 2) {
        #pragma unroll
        for (int t = 0; t < 2; ++t) {
            int p = p0 + t * 16 + lq; if (p > 999) p = 999;
            qA[t] = *(const short8_t*)&Q[(((size_t)bh * 1000 + p) << 4) + quad * 8];
        }
    }
    short8_t onesB = { (short)0x3F80, (short)0x3F80, (short)0x3F80, (short)0x3F80,
                       (short)0x3F80, (short)0x3F80, (short)0x3F80, (short)0x3F80 };

    f32x4 o[2] = { {0.f,0.f,0.f,0.f}, {0.f,0.f,0.f,0.f} };
    f32x4 l[2] = { {0.f,0.f,0.f,0.f}, {0.f,0.f,0.f,0.f} };
    float mrun[2][4];
    #pragma unroll
    for (int t = 0; t < 2; ++t)
        #pragma unroll
        for (int r = 0; r < 4; ++r) mrun[t][r] = -3e38f;

    // per-row mask pointers (lane offset folded in), advanced 32 per chunk
    const float* mp[2][4];
    #pragma unroll
    for (int t = 0; t < 2; ++t)
        #pragma unroll
        for (int r = 0; r < 4; ++r) {
            int p = p0 + t * 16 + quad * 4 + r; if (p > 999) p = 999;
            mp[t][r] = mask + ((size_t)b * 1000 + p) * 1000 + lq;
        }

    for (int n0 = 0; n0 < NN; n0 += 32) {
        const bool tail = (n0 + 32 > NN);   // only n0 == 992
        short8_t kB0 = {}, kB1 = {};
        if (quad < 2) {
            int n_0 = n0 + lq, n_1 = n0 + 16 + lq;
            if (tail) { n_0 = min(n_0, 999); n_1 = min(n_1, 999); }
            kB0 = *(const short8_t*)&K[(((size_t)bh * 1000 + n_0) << 4) + quad * 8];
            kB1 = *(const short8_t*)&K[(((size_t)bh * 1000 + n_1) << 4) + quad * 8];
        }
        // V fragment (B-operand): n = lq (dim), k = key slots n0+quad*8..+7
        // (rows padded to 1024 zeroed slots -> tail reads are exact zeros)
        short8_t vB = *(const short8_t*)&Vt[(((size_t)bh * 16 + lq) << 10) + n0 + quad * 8];

        #pragma unroll
        for (int t = 0; t < 2; ++t) {
            f32x4 zero = {0.f, 0.f, 0.f, 0.f};
            f32x4 s0 = mfma16(qA[t], kB0, zero);
            f32x4 s1 = mfma16(qA[t], kB1, zero);
            float sA[4], sB[4];
            if (!tail) {
                #pragma unroll
                for (int r = 0; r < 4; ++r) {
                    sA[r] = fmaf(s0[r], INV_SQRT_D, mp[t][r][0]);
                    sB[r] = fmaf(s1[r], INV_SQRT_D, mp[t][r][16]);
                }
            } else {
                float mk0 = (lq < 8) ? mp[t][0][0] : 0.f;   // key n0+lq valid iff lq<8
                float mk1 = (lq < 8) ? mp[t][1][0] : 0.f;
                float mk2 = (lq < 8) ? mp[t][2][0] : 0.f;
                float mk3 = (lq < 8) ? mp[t][3][0] : 0.f;
                sA[0] = (lq < 8) ? fmaf(s0[0], INV_SQRT_D, mk0) : -3e38f;
                sA[1] = (lq < 8) ? fmaf(s0[1], INV_SQRT_D, mk1) : -3e38f;
                sA[2] = (lq < 8) ? fmaf(s0[2], INV_SQRT_D, mk2) : -3e38f;
                sA[3] = (lq < 8) ? fmaf(s0[3], INV_SQRT_D, mk3) : -3e38f;
                sB[0] = sB[1] = sB[2] = sB[3] = -3e38f;     // keys 1008+ all invalid
            }
            float alpha[4], nm[4];
            #pragma unroll
            for (int r = 0; r < 4; ++r) {
                float mx = max16(fmaxf(sA[r], sB[r]));
                nm[r] = fmaxf(mrun[t][r], mx);
                alpha[r] = __expf(mrun[t][r] - nm[r]);
                mrun[t][r] = nm[r];
            }
            __threadfence_block();   // order prior LDS reads before overwrite
            #pragma unroll
            for (int r = 0; r < 4; ++r) {
                float e0 = __expf(sA[r] - nm[r]);
                float e1 = __expf(sB[r] - nm[r]);
                Plds[wave][quad * 4 + r][lq] = pack_bf16(e0, e1);
                o[t][r] *= alpha[r];
                l[t][r] *= alpha[r];
            }
            __threadfence_block();   // writes before read-back
            uint4 u4 = *(const uint4*)&Plds[wave][lq][quad * 4];
            short8_t aP = __builtin_bit_cast(short8_t, u4);
            o[t] = mfma16(aP, vB, o[t]);
            l[t] = mfma16(aP, onesB, l[t]);
        }
        #pragma unroll
        for (int t = 0; t < 2; ++t)
            #pragma unroll
            for (int r = 0; r < 4; ++r) mp[t][r] += 32;
    }

    #pragma unroll
    for (int t = 0; t < 2; ++t)
        #pragma unroll
        for (int r = 0; r < 4; ++r) {
            int p = p0 + t * 16 + quad * 4 + r;
            if (p < 1000)
                O[((size_t)b * 1000 + p) * 128 + h * 16 + lq] = o[t][r] / l[t][r];
        }
}

// ---------------------------------------------------------------------------
// K4: combine: gated = g*(att_s@Wc_s + bc_s) + (1-g)*(att_t@Wc_t + bc_t)
// ---------------------------------------------------------------------------
__global__ __launch_bounds__(256) void combine_kernel(
    const float* __restrict__ att_s, const float* __restrict__ att_t,
    const float* __restrict__ Wc_s, const float* __restrict__ bc_s,
    const float* __restrict__ Wc_t, const float* __restrict__ bc_t,
    const float* __restrict__ gate, float* __restrict__ gated)
{
    const int r0 = blockIdx.x * 32;
    __shared__ float As[32][16], At[32][16];
    __shared__ float Ws[16][128], Wt[16][128];
    const int tid = threadIdx.x;
    const int rg = tid >> 5;
    const int cg = tid & 31;
    float accs[4][4] = {}, acct[4][4] = {};

    for (int k0 = 0; k0 < 128; k0 += 16) {
        {
            int t2 = tid & 127, row = t2 >> 2, seg = t2 & 3;
            const float* src = (tid < 128) ? att_s : att_t;
            float* dst = (tid < 128) ? &As[row][seg * 4] : &At[row][seg * 4];
            *(float4*)dst = *(const float4*)&src[(size_t)(r0 + row) * 128 + k0 + seg * 4];
        }
        {
            int kk = tid >> 4, c = (tid & 15) * 8;
            *(float4*)&Ws[kk][c]     = *(const float4*)&Wc_s[(size_t)(k0 + kk) * 128 + c];
            *(float4*)&Ws[kk][c + 4] = *(const float4*)&Wc_s[(size_t)(k0 + kk) * 128 + c + 4];
            *(float4*)&Wt[kk][c]     = *(const float4*)&Wc_t[(size_t)(k0 + kk) * 128 + c];
            *(float4*)&Wt[kk][c + 4] = *(const float4*)&Wc_t[(size_t)(k0 + kk) * 128 + c + 4];
        }
        __syncthreads();
        #pragma unroll
        for (int k = 0; k < 16; ++k) {
            float4 w1 = *(const float4*)&Ws[k][cg * 4];
            float4 w2 = *(const float4*)&Wt[k][cg * 4];
            #pragma unroll
            for (int r = 0; r < 4; ++r) {
                float a1 = As[rg * 4 + r][k];
                float a2 = At[rg * 4 + r][k];
                accs[r][0] = fmaf(a1, w1.x, accs[r][0]);
                accs[r][1] = fmaf(a1, w1.y, accs[r][1]);
                accs[r][2] = fmaf(a1, w1.z, accs[r][2]);
                accs[r][3] = fmaf(a1, w1.w, accs[r][3]);
                acct[r][0] = fmaf(a2, w2.x, acct[r][0]);
                acct[r][1] = fmaf(a2, w2.y, acct[r][1]);
                acct[r][2] = fmaf(a2, w2.z, acct[r][2]);
                acct[r][3] = fmaf(a2, w2.w, acct[r][3]);
            }
        }
        __syncthreads();
    }
    const int c = cg * 4;
    float4 b1 = *(const float4*)&bc_s[c];
    float4 b2 = *(const float4*)&bc_t[c];
    #pragma unroll
    for (int r = 0; r < 4; ++r) {
        int row = r0 + rg * 4 + r;
        float4 g = *(const float4*)&gate[(size_t)row * 128 + c];
        float4 ov;
        ov.x = g.x * (accs[r][0] + b1.x) + (1.f - g.x) * (acct[r][0] + b2.x);
        ov.y = g.y * (accs[r][1] + b1.y) + (1.f - g.y) * (acct[r][1] + b2.y);
        ov.z = g.z * (accs[r][2] + b1.z) + (1.f - g.z) * (acct[r][2] + b2.z);
        ov.w = g.w * (accs[r][3] + b1.w) + (1.f - g.w) * (acct[r][3] + b2.w);
        *(float4*)&gated[(size_t)row * 128 + c] = ov;
    }
}

// ---------------------------------------------------------------------------
// K5: pointer scores (fp32 tiled GEMM + tanh clip + mask), raw scores to out
// ---------------------------------------------------------------------------
__global__ __launch_bounds__(256) void pointer_kernel(
    const float* __restrict__ gated, const float* __restrict__ nodes,
    const float* __restrict__ mask, float* __restrict__ out)
{
    const int b  = blockIdx.z;
    const int p0 = blockIdx.y * 64;
    const int n0 = blockIdx.x * 128;
    __shared__ float As[64][16];
    __shared__ float BsT[16][128];
    const int tid = threadIdx.x;
    const int rg = tid >> 5;
    const int cg = tid & 31;
    float acc[8][4] = {};

    for (int k0 = 0; k0 < 128; k0 += 16) {
        {
            int row = tid >> 2, seg = tid & 3;
            int pp = p0 + row;
            float4 av = make_float4(0.f, 0.f, 0.f, 0.f);
            if (pp < PP) av = *(const float4*)&gated[((size_t)b * PP + pp) * 128 + k0 + seg * 4];
            *(float4*)&As[row][seg * 4] = av;
        }
        {
            int row = tid >> 1, seg = (tid & 1) * 8;
            int nr = n0 + row;
            float4 b0 = make_float4(0.f, 0.f, 0.f, 0.f), b1 = b0;
            if (nr < NN) {
                b0 = *(const float4*)&nodes[((size_t)b * NN + nr) * 128 + k0 + seg];
                b1 = *(const float4*)&nodes[((size_t)b * NN + nr) * 128 + k0 + seg + 4];
            }
            BsT[seg + 0][row] = b0.x; BsT[seg + 1][row] = b0.y;
            BsT[seg + 2][row] = b0.z; BsT[seg + 3][row] = b0.w;
            BsT[seg + 4][row] = b1.x; BsT[seg + 5][row] = b1.y;
            BsT[seg + 6][row] = b1.z; BsT[seg + 7][row] = b1.w;
        }
        __syncthreads();
        #pragma unroll
        for (int k = 0; k < 16; ++k) {
            float4 w = *(const float4*)&BsT[k][cg * 4];
            #pragma unroll
            for (int r = 0; r < 8; ++r) {
                float a = As[rg * 8 + r][k];
                acc[r][0] = fmaf(a, w.x, acc[r][0]);
                acc[r][1] = fmaf(a, w.y, acc[r][1]);
                acc[r][2] = fmaf(a, w.z, acc[r][2]);
                acc[r][3] = fmaf(a, w.w, acc[r][3]);
            }
        }
        __syncthreads();
    }
    const int n = n0 + cg * 4;
    if (n < NN) {
        #pragma unroll
        for (int r = 0; r < 8; ++r) {
            int pp = p0 + rg * 8 + r;
            if (pp < PP) {
                float4 mk = *(const float4*)&mask[((size_t)b * PP + pp) * NN + n];
                float4 ov;
                ov.x = 10.f * tanh_fast(acc[r][0] * INV_SQRT_E) + mk.x;
                ov.y = 10.f * tanh_fast(acc[r][1] * INV_SQRT_E) + mk.y;
                ov.z = 10.f * tanh_fast(acc[r][2] * INV_SQRT_E) + mk.z;
                ov.w = 10.f * tanh_fast(acc[r][3] * INV_SQRT_E) + mk.w;
                *(float4*)&out[((size_t)b * PP + pp) * NN + n] = ov;
            }
        }
    }
}

// ---------------------------------------------------------------------------
// K6: row softmax in-place over d_out [8000, 1000]. One wave per row.
// ---------------------------------------------------------------------------
__global__ __launch_bounds__(256) void softmax_kernel(float* __restrict__ out)
{
    const int row = blockIdx.x * 4 + (threadIdx.x >> 6);
    const int lane = threadIdx.x & 63;
    float* r = out + (size_t)row * NN;
    float v[16];
    float m = -INFINITY;
    #pragma unroll
    for (int j = 0; j < 4; ++j) {
        int n = j * 256 + lane * 4;
        float4 x = make_float4(-INFINITY, -INFINITY, -INFINITY, -INFINITY);
        if (n < NN) x = *(const float4*)&r[n];
        v[j * 4 + 0] = x.x; v[j * 4 + 1] = x.y; v[j * 4 + 2] = x.z; v[j * 4 + 3] = x.w;
        m = fmaxf(m, fmaxf(fmaxf(x.x, x.y), fmaxf(x.z, x.w)));
    }
    #pragma unroll
    for (int off = 1; off < 64; off <<= 1) m = fmaxf(m, __shfl_xor(m, off, 64));
    float sum = 0.f;
    #pragma unroll
    for (int j = 0; j < 16; ++j) { v[j] = __expf(v[j] - m); sum += v[j]; }
    #pragma unroll
    for (int off = 1; off < 64; off <<= 1) sum += __shfl_xor(sum, off, 64);
    float inv = 1.f / sum;
    #pragma unroll
    for (int j = 0; j < 4; ++j) {
        int n = j * 256 + lane * 4;
        if (n < NN) {
            *(float4*)&r[n] = make_float4(v[j * 4 + 0] * inv, v[j * 4 + 1] * inv,
                                          v[j * 4 + 2] * inv, v[j * 4 + 3] * inv);
        }
    }
}

// ---------------------------------------------------------------------------
extern "C" void kernel_launch(void* const* d_in, const int* in_sizes, int n_in,
                              void* d_out, int out_size, void* d_ws, size_t ws_size,
                              hipStream_t stream)
{
    const float* eln   = (const float*)d_in[0];
    const float* attr  = (const float*)d_in[1];
    const float* nodes = (const float*)d_in[2];
    const float* mask  = (const float*)d_in[3];
    const float* Wq_s  = (const float*)d_in[4];
    const float* Wk_s  = (const float*)d_in[5];
    const float* Wv_s  = (const float*)d_in[6];
    const float* Wq_t  = (const float*)d_in[7];
    const float* Wk_t  = (const float*)d_in[8];
    const float* Wv_t  = (const float*)d_in[9];
    const float* Wc_s  = (const float*)d_in[10];
    const float* bc_s  = (const float*)d_in[11];
    const float* Wc_t  = (const float*)d_in[12];
    const float* bc_t  = (const float*)d_in[13];
    const float* Wg    = (const float*)d_in[14];
    const float* bg    = (const float*)d_in[15];
    float* out = (float*)d_out;

    char* w = (char*)d_ws;
    const size_t KB_SZ = (size_t)64 * 1000 * 16 * 2;   // 2,048,000 B
    const size_t VT_SZ = (size_t)64 * 16 * 1024 * 2;   // 2,097,152 B
    const size_t F_SZ  = (size_t)8000 * 128 * 4;       // 4,096,000 B
    __bf16* kb_s = (__bf16*)w;            w += KB_SZ;
    __bf16* kb_t = (__bf16*)w;            w += KB_SZ;
    __bf16* qb_s = (__bf16*)w;            w += KB_SZ;
    __bf16* qb_t = (__bf16*)w;            w += KB_SZ;
    __bf16* vt_s = (__bf16*)w;            w += VT_SZ;
    __bf16* vt_t = (__bf16*)w;            w += VT_SZ;
    float* gate  = (float*)w;             w += F_SZ;
    float* att_s = (float*)w;             w += F_SZ;
    float* att_t = (float*)w;             w += F_SZ;
    float* gated = (float*)w;             w += F_SZ;

    // zero V-transposed pads (slots >= valid keys) so tail B-frags are 0
    hipMemsetAsync(vt_s, 0, 2 * VT_SZ, stream);

    kv_proj_kernel<<<dim3(125, 4), 256, 0, stream>>>(
        nodes, Wk_s, Wv_s, Wk_t, Wv_t, kb_s, vt_s, kb_t, vt_t);
    q_proj_kernel<<<dim3(125, 3), 256, 0, stream>>>(
        eln, attr, Wq_s, Wq_t, Wg, bg, qb_s, qb_t, gate);
    attn_mfma_kernel<<<dim3(32, 4, 8), 256, 0, stream>>>(
        qb_s, qb_t, kb_s, kb_t, vt_s, vt_t, mask, att_s, att_t);
    combine_kernel<<<dim3(250), 256, 0, stream>>>(
        att_s, att_t, Wc_s, bc_s, Wc_t, bc_t, gate, gated);
    pointer_kernel<<<dim3(8, 16, 8), 256, 0, stream>>>(
        gated, nodes, mask, out);
    softmax_kernel<<<dim3(2000), 256, 0, stream>>>(out);
}

// Round 3
// 283.429 us; speedup vs baseline: 1.5556x; 1.1130x over previous
//
#include <hip/hip_runtime.h>
#include <math.h>

#define BB 8
#define PP 1000
#define NN 1000
#define EE 128
#define HH 8
#define DD 16

#define INV_SQRT_E 0.08838834764831845f   // 1/sqrt(128)
#define INV_SQRT_D 0.25f                   // 1/sqrt(16)

typedef short short8_t __attribute__((ext_vector_type(8)));
typedef float f32x4    __attribute__((ext_vector_type(4)));
typedef __bf16 bf16x4  __attribute__((ext_vector_type(4)));

__device__ __forceinline__ float sigmoid_fast(float x) {
    return 1.f / (1.f + __expf(-x));
}
__device__ __forceinline__ float tanh_fast(float x) {
    x = fminf(fmaxf(x, -15.f), 15.f);
    float e = __expf(2.f * x);
    return (e - 1.f) / (e + 1.f);
}

__device__ __forceinline__ f32x4 mfma16(short8_t a, short8_t b, f32x4 c) {
    return __builtin_amdgcn_mfma_f32_16x16x32_bf16(a, b, c, 0, 0, 0);
}

__device__ __forceinline__ unsigned int pack_bf16(float a, float b) {
    __bf16 x = (__bf16)a, y = (__bf16)b;
    unsigned short ux = __builtin_bit_cast(unsigned short, x);
    unsigned short uy = __builtin_bit_cast(unsigned short, y);
    return (unsigned int)ux | ((unsigned int)uy << 16);
}

// ---------------------------------------------------------------------------
// K1: kv projections -> bf16. K stored [bh][n][d]. V stored TRANSPOSED +
// key-permuted: [bh][d][pos] (1024-slot rows; within each 32-key block,
// key r<16 -> slot 2r, r>=16 -> slot 2(r-16)+1, matching packed-pair P).
// ---------------------------------------------------------------------------
__global__ __launch_bounds__(256) void kv_proj_kernel(
    const float* __restrict__ A,
    const float* __restrict__ Wk_s, const float* __restrict__ Wv_s,
    const float* __restrict__ Wk_t, const float* __restrict__ Wv_t,
    __bf16* __restrict__ kb_s, __bf16* __restrict__ vt_s,
    __bf16* __restrict__ kb_t, __bf16* __restrict__ vt_t)
{
    const int wsel = blockIdx.y;
    const float* W = (wsel == 0) ? Wk_s : (wsel == 1) ? Wv_s : (wsel == 2) ? Wk_t : Wv_t;
    __bf16* KO = (wsel == 0) ? kb_s : kb_t;
    __bf16* VO = (wsel == 1) ? vt_s : vt_t;
    const int r0 = blockIdx.x * 64;
    __shared__ float As[64][16];
    __shared__ float Ws[16][128];
    const int tid = threadIdx.x;
    const int rg = tid >> 5;
    const int cg = tid & 31;
    float acc[8][4] = {};

    for (int k0 = 0; k0 < 128; k0 += 16) {
        {
            int row = tid >> 2, seg = tid & 3;
            float4 av = *(const float4*)&A[(size_t)(r0 + row) * 128 + k0 + seg * 4];
            *(float4*)&As[row][seg * 4] = av;
        }
        {
            int kk = tid >> 4, c = (tid & 15) * 8;
            *(float4*)&Ws[kk][c]     = *(const float4*)&W[(size_t)(k0 + kk) * 128 + c];
            *(float4*)&Ws[kk][c + 4] = *(const float4*)&W[(size_t)(k0 + kk) * 128 + c + 4];
        }
        __syncthreads();
        #pragma unroll
        for (int k = 0; k < 16; ++k) {
            float4 w = *(const float4*)&Ws[k][cg * 4];
            #pragma unroll
            for (int r = 0; r < 8; ++r) {
                float a = As[rg * 8 + r][k];
                acc[r][0] = fmaf(a, w.x, acc[r][0]);
                acc[r][1] = fmaf(a, w.y, acc[r][1]);
                acc[r][2] = fmaf(a, w.z, acc[r][2]);
                acc[r][3] = fmaf(a, w.w, acc[r][3]);
            }
        }
        __syncthreads();
    }
    const int c = cg * 4;
    const int h = c >> 4, d = c & 15;
    if ((wsel & 1) == 0) {
        #pragma unroll
        for (int r = 0; r < 8; ++r) {
            int row = r0 + rg * 8 + r;
            int b = row / 1000, n = row % 1000;
            bf16x4 pk = { (__bf16)acc[r][0], (__bf16)acc[r][1],
                          (__bf16)acc[r][2], (__bf16)acc[r][3] };
            *(bf16x4*)&KO[(((size_t)(b * HH + h) * 1000 + n) << 4) + d] = pk;
        }
    } else {
        #pragma unroll
        for (int r = 0; r < 8; ++r) {
            int row = r0 + rg * 8 + r;
            int b = row / 1000, n = row % 1000;
            int rr = n & 31;
            int pos = (n & ~31) + ((rr < 16) ? (rr << 1) : (((rr - 16) << 1) | 1));
            #pragma unroll
            for (int i = 0; i < 4; ++i) {
                VO[((size_t)((b * HH + h) * 16 + d + i) << 10) + pos] = (__bf16)acc[r][i];
            }
        }
    }
}

// ---------------------------------------------------------------------------
// K2: q_shared / q_task (bf16, [bh][p][d]) and gate (fp32) projections.
// ---------------------------------------------------------------------------
__global__ __launch_bounds__(256) void q_proj_kernel(
    const float* __restrict__ eln, const float* __restrict__ attr,
    const float* __restrict__ Wq_s, const float* __restrict__ Wq_t,
    const float* __restrict__ Wg, const float* __restrict__ bg,
    __bf16* __restrict__ qb_s, __bf16* __restrict__ qb_t, float* __restrict__ gate)
{
    const int wsel = blockIdx.y;
    const float* W = (wsel == 0) ? Wq_s : (wsel == 1) ? Wq_t : Wg;
    const int r0 = blockIdx.x * 64;
    __shared__ float As[64][16];
    __shared__ float Ws[16][128];
    const int tid = threadIdx.x;
    const int rg = tid >> 5;
    const int cg = tid & 31;
    float acc[8][4] = {};

    for (int k0 = 0; k0 < 144; k0 += 16) {
        {
            int row = tid >> 2, seg = tid & 3;
            int k = k0 + seg * 4;
            float4 av = make_float4(0.f, 0.f, 0.f, 0.f);
            if (k + 3 < 128)      av = *(const float4*)&eln[(size_t)(r0 + row) * 128 + k];
            else if (k == 128)    av = *(const float4*)&attr[(size_t)(r0 + row) * 4];
            *(float4*)&As[row][seg * 4] = av;
        }
        {
            int kk = tid >> 4, c = (tid & 15) * 8;
            int k = k0 + kk;
            float4 w0 = make_float4(0.f, 0.f, 0.f, 0.f), w1 = w0;
            if (k < 132) {
                w0 = *(const float4*)&W[(size_t)k * 128 + c];
                w1 = *(const float4*)&W[(size_t)k * 128 + c + 4];
            }
            *(float4*)&Ws[kk][c]     = w0;
            *(float4*)&Ws[kk][c + 4] = w1;
        }
        __syncthreads();
        #pragma unroll
        for (int k = 0; k < 16; ++k) {
            float4 w = *(const float4*)&Ws[k][cg * 4];
            #pragma unroll
            for (int r = 0; r < 8; ++r) {
                float a = As[rg * 8 + r][k];
                acc[r][0] = fmaf(a, w.x, acc[r][0]);
                acc[r][1] = fmaf(a, w.y, acc[r][1]);
                acc[r][2] = fmaf(a, w.z, acc[r][2]);
                acc[r][3] = fmaf(a, w.w, acc[r][3]);
            }
        }
        __syncthreads();
    }
    const int c = cg * 4;
    if (wsel < 2) {
        __bf16* Qo = (wsel == 0) ? qb_s : qb_t;
        const int h = c >> 4, d = c & 15;
        #pragma unroll
        for (int r = 0; r < 8; ++r) {
            int row = r0 + rg * 8 + r;
            int b = row / 1000, p = row % 1000;
            bf16x4 pk = { (__bf16)acc[r][0], (__bf16)acc[r][1],
                          (__bf16)acc[r][2], (__bf16)acc[r][3] };
            *(bf16x4*)&Qo[(((size_t)(b * HH + h) * 1000 + p) << 4) + d] = pk;
        }
    } else {
        float4 bgv = *(const float4*)&bg[c];
        #pragma unroll
        for (int r = 0; r < 8; ++r) {
            int row = r0 + rg * 8 + r;
            float4 g;
            g.x = sigmoid_fast(acc[r][0] + bgv.x);
            g.y = sigmoid_fast(acc[r][1] + bgv.y);
            g.z = sigmoid_fast(acc[r][2] + bgv.z);
            g.w = sigmoid_fast(acc[r][3] + bgv.w);
            *(float4*)&gate[(size_t)row * 128 + c] = g;
        }
    }
}

// ---------------------------------------------------------------------------
// K3: MFMA flash attention, NO online rescaling (scores are small; exp w/o
// max-subtraction is exact same math). l via MFMA vs ones-fragment.
// ---------------------------------------------------------------------------
__global__ __launch_bounds__(256) void attn_mfma_kernel(
    const __bf16* __restrict__ qb_s, const __bf16* __restrict__ qb_t,
    const __bf16* __restrict__ kb_s, const __bf16* __restrict__ kb_t,
    const __bf16* __restrict__ vt_s, const __bf16* __restrict__ vt_t,
    const float* __restrict__ mask,
    float* __restrict__ att_s, float* __restrict__ att_t)
{
    const int b    = blockIdx.z;
    const int wave = threadIdx.x >> 6;
    const int combo = blockIdx.y * 4 + wave;
    const int br = combo & 1;
    const int h  = combo >> 1;
    const __bf16* Q  = br ? qb_t : qb_s;
    const __bf16* K  = br ? kb_t : kb_s;
    const __bf16* Vt = br ? vt_t : vt_s;
    float* O         = br ? att_t : att_s;
    const int lane = threadIdx.x & 63;
    const int quad = lane >> 4, lq = lane & 15;
    const int bh = b * HH + h;
    const int p0 = blockIdx.x * 32;

    __shared__ unsigned int Plds[4][16][20];   // per-wave 16 rows x 16 uints, +4 pad

    short8_t qA[2] = {};
    if (quad < 2) {
        #pragma unroll
        for (int t = 0; t < 2; ++t) {
            int p = p0 + t * 16 + lq; if (p > 999) p = 999;
            qA[t] = *(const short8_t*)&Q[(((size_t)bh * 1000 + p) << 4) + quad * 8];
        }
    }
    short8_t onesB = { (short)0x3F80, (short)0x3F80, (short)0x3F80, (short)0x3F80,
                       (short)0x3F80, (short)0x3F80, (short)0x3F80, (short)0x3F80 };

    f32x4 o[2] = { {0.f,0.f,0.f,0.f}, {0.f,0.f,0.f,0.f} };
    f32x4 l[2] = { {0.f,0.f,0.f,0.f}, {0.f,0.f,0.f,0.f} };

    const float* mp[2][4];
    #pragma unroll
    for (int t = 0; t < 2; ++t)
        #pragma unroll
        for (int r = 0; r < 4; ++r) {
            int p = p0 + t * 16 + quad * 4 + r; if (p > 999) p = 999;
            mp[t][r] = mask + ((size_t)b * 1000 + p) * 1000 + lq;
        }

    for (int n0 = 0; n0 < NN; n0 += 32) {
        const bool tail = (n0 + 32 > NN);   // only n0 == 992
        short8_t kB0 = {}, kB1 = {};
        if (quad < 2) {
            int n_0 = n0 + lq, n_1 = n0 + 16 + lq;
            if (tail) { n_0 = min(n_0, 999); n_1 = min(n_1, 999); }
            kB0 = *(const short8_t*)&K[(((size_t)bh * 1000 + n_0) << 4) + quad * 8];
            kB1 = *(const short8_t*)&K[(((size_t)bh * 1000 + n_1) << 4) + quad * 8];
        }
        short8_t vB = *(const short8_t*)&Vt[(((size_t)bh * 16 + lq) << 10) + n0 + quad * 8];

        #pragma unroll
        for (int t = 0; t < 2; ++t) {
            f32x4 zero = {0.f, 0.f, 0.f, 0.f};
            f32x4 s0 = mfma16(qA[t], kB0, zero);
            f32x4 s1 = mfma16(qA[t], kB1, zero);
            float e0[4], e1[4];
            if (!tail) {
                #pragma unroll
                for (int r = 0; r < 4; ++r) {
                    e0[r] = __expf(fmaf(s0[r], INV_SQRT_D, mp[t][r][0]));
                    e1[r] = __expf(fmaf(s1[r], INV_SQRT_D, mp[t][r][16]));
                }
            } else {
                #pragma unroll
                for (int r = 0; r < 4; ++r) {
                    float mk = (lq < 8) ? mp[t][r][0] : 0.f;     // predicated: no OOB
                    e0[r] = (lq < 8) ? __expf(fmaf(s0[r], INV_SQRT_D, mk)) : 0.f;
                    e1[r] = 0.f;
                }
            }
            __threadfence_block();   // order prior LDS reads before overwrite
            #pragma unroll
            for (int r = 0; r < 4; ++r)
                Plds[wave][quad * 4 + r][lq] = pack_bf16(e0[r], e1[r]);
            __threadfence_block();   // writes before read-back
            uint4 u4 = *(const uint4*)&Plds[wave][lq][quad * 4];
            short8_t aP = __builtin_bit_cast(short8_t, u4);
            o[t] = mfma16(aP, vB, o[t]);
            l[t] = mfma16(aP, onesB, l[t]);
        }
        #pragma unroll
        for (int t = 0; t < 2; ++t)
            #pragma unroll
            for (int r = 0; r < 4; ++r) mp[t][r] += 32;
    }

    #pragma unroll
    for (int t = 0; t < 2; ++t)
        #pragma unroll
        for (int r = 0; r < 4; ++r) {
            int p = p0 + t * 16 + quad * 4 + r;
            if (p < 1000)
                O[((size_t)b * 1000 + p) * 128 + h * 16 + lq] = o[t][r] / l[t][r];
        }
}

// ---------------------------------------------------------------------------
// K4: combine -> gated in BF16 (consumed by MFMA pointer kernel)
// ---------------------------------------------------------------------------
__global__ __launch_bounds__(256) void combine_kernel(
    const float* __restrict__ att_s, const float* __restrict__ att_t,
    const float* __restrict__ Wc_s, const float* __restrict__ bc_s,
    const float* __restrict__ Wc_t, const float* __restrict__ bc_t,
    const float* __restrict__ gate, __bf16* __restrict__ gatedb)
{
    const int r0 = blockIdx.x * 32;
    __shared__ float As[32][16], At[32][16];
    __shared__ float Ws[16][128], Wt[16][128];
    const int tid = threadIdx.x;
    const int rg = tid >> 5;
    const int cg = tid & 31;
    float accs[4][4] = {}, acct[4][4] = {};

    for (int k0 = 0; k0 < 128; k0 += 16) {
        {
            int t2 = tid & 127, row = t2 >> 2, seg = t2 & 3;
            const float* src = (tid < 128) ? att_s : att_t;
            float* dst = (tid < 128) ? &As[row][seg * 4] : &At[row][seg * 4];
            *(float4*)dst = *(const float4*)&src[(size_t)(r0 + row) * 128 + k0 + seg * 4];
        }
        {
            int kk = tid >> 4, c = (tid & 15) * 8;
            *(float4*)&Ws[kk][c]     = *(const float4*)&Wc_s[(size_t)(k0 + kk) * 128 + c];
            *(float4*)&Ws[kk][c + 4] = *(const float4*)&Wc_s[(size_t)(k0 + kk) * 128 + c + 4];
            *(float4*)&Wt[kk][c]     = *(const float4*)&Wc_t[(size_t)(k0 + kk) * 128 + c];
            *(float4*)&Wt[kk][c + 4] = *(const float4*)&Wc_t[(size_t)(k0 + kk) * 128 + c + 4];
        }
        __syncthreads();
        #pragma unroll
        for (int k = 0; k < 16; ++k) {
            float4 w1 = *(const float4*)&Ws[k][cg * 4];
            float4 w2 = *(const float4*)&Wt[k][cg * 4];
            #pragma unroll
            for (int r = 0; r < 4; ++r) {
                float a1 = As[rg * 4 + r][k];
                float a2 = At[rg * 4 + r][k];
                accs[r][0] = fmaf(a1, w1.x, accs[r][0]);
                accs[r][1] = fmaf(a1, w1.y, accs[r][1]);
                accs[r][2] = fmaf(a1, w1.z, accs[r][2]);
                accs[r][3] = fmaf(a1, w1.w, accs[r][3]);
                acct[r][0] = fmaf(a2, w2.x, acct[r][0]);
                acct[r][1] = fmaf(a2, w2.y, acct[r][1]);
                acct[r][2] = fmaf(a2, w2.z, acct[r][2]);
                acct[r][3] = fmaf(a2, w2.w, acct[r][3]);
            }
        }
        __syncthreads();
    }
    const int c = cg * 4;
    float4 b1 = *(const float4*)&bc_s[c];
    float4 b2 = *(const float4*)&bc_t[c];
    #pragma unroll
    for (int r = 0; r < 4; ++r) {
        int row = r0 + rg * 4 + r;
        float4 g = *(const float4*)&gate[(size_t)row * 128 + c];
        float ox = g.x * (accs[r][0] + b1.x) + (1.f - g.x) * (acct[r][0] + b2.x);
        float oy = g.y * (accs[r][1] + b1.y) + (1.f - g.y) * (acct[r][1] + b2.y);
        float oz = g.z * (accs[r][2] + b1.z) + (1.f - g.z) * (acct[r][2] + b2.z);
        float ow = g.w * (accs[r][3] + b1.w) + (1.f - g.w) * (acct[r][3] + b2.w);
        bf16x4 pk = { (__bf16)ox, (__bf16)oy, (__bf16)oz, (__bf16)ow };
        *(bf16x4*)&gatedb[(size_t)row * 128 + c] = pk;
    }
}

// ---------------------------------------------------------------------------
// K4b: nodes fp32 -> bf16 (row-major [b][n][128])
// ---------------------------------------------------------------------------
__global__ __launch_bounds__(256) void to_bf16_kernel(
    const float* __restrict__ in, __bf16* __restrict__ outb)
{
    int i = (blockIdx.x * 256 + threadIdx.x) * 4;
    float4 v = *(const float4*)&in[i];
    bf16x4 pk = { (__bf16)v.x, (__bf16)v.y, (__bf16)v.z, (__bf16)v.w };
    *(bf16x4*)&outb[i] = pk;
}

// ---------------------------------------------------------------------------
// K5: MFMA pointer scores. Wave = 16p x 64n tile; block = 4 waves (64p x 64n).
// A-frag: gated_bf16 rows (contiguous 16B). B-frag: nodes_bf16 rows
// (contiguous 16B; B[k][n] = nodes[n][k]). Epilogue: 10*tanh(s/sqrt(E)) + mask.
// ---------------------------------------------------------------------------
__global__ __launch_bounds__(256) void pointer_mfma_kernel(
    const __bf16* __restrict__ gb, const __bf16* __restrict__ nb,
    const float* __restrict__ mask, float* __restrict__ out)
{
    const int b    = blockIdx.z;
    const int wave = threadIdx.x >> 6;
    const int lane = threadIdx.x & 63;
    const int quad = lane >> 4, lq = lane & 15;
    const int p0 = blockIdx.y * 64 + wave * 16;
    const int n0 = blockIdx.x * 64;

    // A fragments over 4 K-chunks
    short8_t aF[4];
    {
        int pp = p0 + lq; if (pp > 999) pp = 999;
        const __bf16* arow = gb + (((size_t)b * 1000 + pp) << 7) + quad * 8;
        #pragma unroll
        for (int kc = 0; kc < 4; ++kc) aF[kc] = *(const short8_t*)&arow[kc * 32];
    }
    f32x4 acc[4] = { {0.f,0.f,0.f,0.f}, {0.f,0.f,0.f,0.f},
                     {0.f,0.f,0.f,0.f}, {0.f,0.f,0.f,0.f} };
    #pragma unroll
    for (int nt = 0; nt < 4; ++nt) {
        int nn = n0 + nt * 16 + lq; if (nn > 999) nn = 999;
        const __bf16* brow = nb + (((size_t)b * 1000 + nn) << 7) + quad * 8;
        #pragma unroll
        for (int kc = 0; kc < 4; ++kc) {
            short8_t bF = *(const short8_t*)&brow[kc * 32];
            acc[nt] = mfma16(aF[kc], bF, acc[nt]);
        }
    }
    // epilogue: C layout col=lq (n), row=quad*4+r (p)
    #pragma unroll
    for (int nt = 0; nt < 4; ++nt) {
        int n = n0 + nt * 16 + lq;
        #pragma unroll
        for (int r = 0; r < 4; ++r) {
            int p = p0 + quad * 4 + r;
            if (p < 1000 && n < 1000) {
                size_t idx = ((size_t)b * 1000 + p) * 1000 + n;
                out[idx] = 10.f * tanh_fast(acc[nt][r] * INV_SQRT_E) + mask[idx];
            }
        }
    }
}

// ---------------------------------------------------------------------------
// K6: row softmax in-place over d_out [8000, 1000]. One wave per row.
// ---------------------------------------------------------------------------
__global__ __launch_bounds__(256) void softmax_kernel(float* __restrict__ out)
{
    const int row = blockIdx.x * 4 + (threadIdx.x >> 6);
    const int lane = threadIdx.x & 63;
    float* r = out + (size_t)row * NN;
    float v[16];
    float m = -INFINITY;
    #pragma unroll
    for (int j = 0; j < 4; ++j) {
        int n = j * 256 + lane * 4;
        float4 x = make_float4(-INFINITY, -INFINITY, -INFINITY, -INFINITY);
        if (n < NN) x = *(const float4*)&r[n];
        v[j * 4 + 0] = x.x; v[j * 4 + 1] = x.y; v[j * 4 + 2] = x.z; v[j * 4 + 3] = x.w;
        m = fmaxf(m, fmaxf(fmaxf(x.x, x.y), fmaxf(x.z, x.w)));
    }
    #pragma unroll
    for (int off = 1; off < 64; off <<= 1) m = fmaxf(m, __shfl_xor(m, off, 64));
    float sum = 0.f;
    #pragma unroll
    for (int j = 0; j < 16; ++j) { v[j] = __expf(v[j] - m); sum += v[j]; }
    #pragma unroll
    for (int off = 1; off < 64; off <<= 1) sum += __shfl_xor(sum, off, 64);
    float inv = 1.f / sum;
    #pragma unroll
    for (int j = 0; j < 4; ++j) {
        int n = j * 256 + lane * 4;
        if (n < NN) {
            *(float4*)&r[n] = make_float4(v[j * 4 + 0] * inv, v[j * 4 + 1] * inv,
                                          v[j * 4 + 2] * inv, v[j * 4 + 3] * inv);
        }
    }
}

// ---------------------------------------------------------------------------
extern "C" void kernel_launch(void* const* d_in, const int* in_sizes, int n_in,
                              void* d_out, int out_size, void* d_ws, size_t ws_size,
                              hipStream_t stream)
{
    const float* eln   = (const float*)d_in[0];
    const float* attr  = (const float*)d_in[1];
    const float* nodes = (const float*)d_in[2];
    const float* mask  = (const float*)d_in[3];
    const float* Wq_s  = (const float*)d_in[4];
    const float* Wk_s  = (const float*)d_in[5];
    const float* Wv_s  = (const float*)d_in[6];
    const float* Wq_t  = (const float*)d_in[7];
    const float* Wk_t  = (const float*)d_in[8];
    const float* Wv_t  = (const float*)d_in[9];
    const float* Wc_s  = (const float*)d_in[10];
    const float* bc_s  = (const float*)d_in[11];
    const float* Wc_t  = (const float*)d_in[12];
    const float* bc_t  = (const float*)d_in[13];
    const float* Wg    = (const float*)d_in[14];
    const float* bg    = (const float*)d_in[15];
    float* out = (float*)d_out;

    char* w = (char*)d_ws;
    const size_t KB_SZ = (size_t)64 * 1000 * 16 * 2;   // 2,048,000 B
    const size_t VT_SZ = (size_t)64 * 16 * 1024 * 2;   // 2,097,152 B
    const size_t F_SZ  = (size_t)8000 * 128 * 4;       // 4,096,000 B
    const size_t H_SZ  = (size_t)8000 * 128 * 2;       // 2,048,000 B
    __bf16* kb_s = (__bf16*)w;            w += KB_SZ;
    __bf16* kb_t = (__bf16*)w;            w += KB_SZ;
    __bf16* qb_s = (__bf16*)w;            w += KB_SZ;
    __bf16* qb_t = (__bf16*)w;            w += KB_SZ;
    __bf16* vt_s = (__bf16*)w;            w += VT_SZ;
    __bf16* vt_t = (__bf16*)w;            w += VT_SZ;
    float* gate  = (float*)w;             w += F_SZ;
    float* att_s = (float*)w;             w += F_SZ;
    float* att_t = (float*)w;             w += F_SZ;
    __bf16* gatedb = (__bf16*)w;          w += H_SZ;
    __bf16* nodesb = (__bf16*)w;          w += H_SZ;

    // zero V-transposed pads so tail B-frags are exact zeros
    hipMemsetAsync(vt_s, 0, 2 * VT_SZ, stream);

    kv_proj_kernel<<<dim3(125, 4), 256, 0, stream>>>(
        nodes, Wk_s, Wv_s, Wk_t, Wv_t, kb_s, vt_s, kb_t, vt_t);
    to_bf16_kernel<<<dim3(1000), 256, 0, stream>>>(nodes, nodesb);
    q_proj_kernel<<<dim3(125, 3), 256, 0, stream>>>(
        eln, attr, Wq_s, Wq_t, Wg, bg, qb_s, qb_t, gate);
    attn_mfma_kernel<<<dim3(32, 4, 8), 256, 0, stream>>>(
        qb_s, qb_t, kb_s, kb_t, vt_s, vt_t, mask, att_s, att_t);
    combine_kernel<<<dim3(250), 256, 0, stream>>>(
        att_s, att_t, Wc_s, bc_s, Wc_t, bc_t, gate, gatedb);
    pointer_mfma_kernel<<<dim3(16, 16, 8), 256, 0, stream>>>(
        gatedb, nodesb, mask, out);
    softmax_kernel<<<dim3(2000), 256, 0, stream>>>(out);
}